// Round 1
// baseline (866.354 us; speedup 1.0000x reference)
//
#include <hip/hip_runtime.h>

// Projection: per row i (128 fp32): sq = ||x_i||^2, s = (sq-1)/(sq+1),
// out row = [(1-s)*x_i, s]  (output row stride 129).
//
// Memory-bound streaming kernel: 512 MiB read + 516 MiB write.
// Layout: one 32-lane half-wave per row. Each lane loads one float4
// (32 lanes * 16 B = 512 B = one full row, coalesced). Row-sum via
// 5x __shfl_xor (masks 1..16 stay inside the 32-lane half on wave64).
// Stores are scalar dwords because the 129-float row stride breaks
// 16B alignment for 3/4 of rows; 64 lanes of dword stores still cover
// contiguous 512B spans per half-wave.

__global__ __launch_bounds__(256) void Projection_77936476553267_kernel(
    const float* __restrict__ x, float* __restrict__ out, int n_rows) {
    constexpr int D = 128;

    const int tid    = blockIdx.x * blockDim.x + threadIdx.x;
    const int wave   = tid >> 6;              // global wave id
    const int lane   = threadIdx.x & 63;
    const int half   = lane >> 5;             // 0 or 1: which row of the pair
    const int sub    = lane & 31;             // lane within the half-wave
    const int nwaves = (gridDim.x * blockDim.x) >> 6;

    for (int row = wave * 2 + half; row < n_rows; row += nwaves * 2) {
        const float4* xr = (const float4*)(x + (size_t)row * D);
        float4 v = xr[sub];                   // 512 B contiguous per half-wave

        float sq = v.x * v.x + v.y * v.y + v.z * v.z + v.w * v.w;
        // reduce across the 32 lanes of this half (xor masks < 32 stay in-half)
        #pragma unroll
        for (int m = 16; m >= 1; m >>= 1)
            sq += __shfl_xor(sq, m, 64);

        float s     = -(1.0f - sq) / (1.0f + sq);
        float scale = 1.0f - s;               // = 2/(1+sq)

        float* orow = out + (size_t)row * (D + 1);
        const int c = sub * 4;
        orow[c + 0] = scale * v.x;
        orow[c + 1] = scale * v.y;
        orow[c + 2] = scale * v.z;
        orow[c + 3] = scale * v.w;
        if (sub == 0) orow[D] = s;
    }
}

extern "C" void kernel_launch(void* const* d_in, const int* in_sizes, int n_in,
                              void* d_out, int out_size, void* d_ws, size_t ws_size,
                              hipStream_t stream) {
    const float* x = (const float*)d_in[0];
    float* out     = (float*)d_out;
    const int n_rows = in_sizes[0] / 128;

    const int block = 256;
    const int grid  = 8192;  // 32 blocks/CU-equivalent; grid-stride covers 1M rows
    Projection_77936476553267_kernel<<<grid, block, 0, stream>>>(x, out, n_rows);
}